// Round 12
// baseline (21.195 us; speedup 1.0000x reference)
//
#include <hip/hip_runtime.h>
#include <math.h>

#define B_  4
#define CI  8
#define HH  128
#define WW  128
#define CO  16
#define KH  5
#define KW  5
#define HO  124
#define WO  124

#define TILE_X 16     // px cols per block (8 tx-groups of 2 px)
#define TILE_Y 8      // px rows per block
#define ROWF   20     // LDS img row: 16 + 4 halo floats
#define THREADS 512   // 8 waves; wave w owns o-pair {2w, 2w+1}

using f32x2 = __attribute__((ext_vector_type(2))) float;

__global__ __launch_bounds__(THREADS, 4)
void maxplus_conv12(const float* __restrict__ img,
                    const float* __restrict__ kern,
                    float* __restrict__ out)
{
    // img tile rows y0..y0+11, cols x0..x0+19, -INF outside. 8*12*20*4 = 7.7 KB
    __shared__ __align__(16) float ilds[CI][TILE_Y + KH - 1][ROWF];
    // weights: pre-flipped, o-pair-interleaved float2: [opair][c][tap] = 8*8*25*8B = 12.8 KB
    __shared__ __align__(8) f32x2 wlds[8 * CI * 25];

    const int tid = threadIdx.x;
    const int x0  = blockIdx.x * TILE_X;
    const int y0  = blockIdx.y * TILE_Y;
    const int b   = blockIdx.z;

    // ---- stage img tile: 8c * 12r * 5 f4 = 480 float4 ----
    const float* imgb = img + (size_t)b * CI * HH * WW;
    if (tid < CI * 12 * 5) {
        const int c   = tid / 60;
        const int rem = tid - c * 60;
        const int r   = rem / 5;
        const int f4  = rem - r * 5;
        const int gy = y0 + r;
        const int gx = x0 + f4 * 4;         // 16B-aligned
        float4 v;
        if (gy < HH && gx < WW) {
            v = *(const float4*)&imgb[(c * HH + gy) * WW + gx];
        } else {
            v.x = v.y = v.z = v.w = -INFINITY;
        }
        *(float4*)&ilds[c][r][f4 * 4] = v;
    }
    // ---- stage weight pairs: 8 opairs * 8 c * 25 taps = 1600 float2 ----
    for (int idx = tid; idx < 8 * CI * 25; idx += THREADS) {
        const int t  = idx % 25;            // pre-flipped tap index: t = i*5+j <-> (4-i,4-j)
        const int cc = (idx / 25) & 7;
        const int op = idx / (25 * CI);
        const int src = cc * 25 + (24 - t);
        f32x2 wv;
        wv.x = kern[(2 * op)     * (CI * KH * KW) + src];
        wv.y = kern[(2 * op + 1) * (CI * KH * KW) + src];
        wlds[idx] = wv;
    }
    __syncthreads();

    const int lane = tid & 63;
    const int tx   = lane & 7;          // 2 px: x = x0 + tx*2 + {0,1}
    const int ty   = lane >> 3;         // output row y0 + ty
    const int wave = tid >> 6;          // o-pair index (wave-uniform)
    const f32x2* wbase = &wlds[wave * (CI * 25)];

    f32x2 acc0 = {-INFINITY, -INFINITY};   // px0: {o0, o1}
    f32x2 acc1 = {-INFINITY, -INFINITY};   // px1: {o0, o1}

    #pragma unroll 1
    for (int c = 0; c < CI; ++c) {
        // img window: 3 x ds_read_b64 per row, all 5 rows up front (30 VGPR)
        float2 vA[5], vB[5], vC[5];
        #pragma unroll
        for (int i = 0; i < KH; ++i) {
            const float* vp = &ilds[c][ty + i][tx * 2];
            vA[i] = *(const float2*)vp;
            vB[i] = *(const float2*)(vp + 2);
            vC[i] = *(const float2*)(vp + 4);
        }
        #pragma unroll
        for (int i = 0; i < KH; ++i) {
            // this row's 5 weight pairs: broadcast ds_read_b64 into VGPR pairs
            f32x2 wp0 = wbase[c * 25 + i * 5 + 0];
            f32x2 wp1 = wbase[c * 25 + i * 5 + 1];
            f32x2 wp2 = wbase[c * 25 + i * 5 + 2];
            f32x2 wp3 = wbase[c * 25 + i * 5 + 3];
            f32x2 wp4 = wbase[c * 25 + i * 5 + 4];
            const float v[6] = {vA[i].x, vA[i].y, vB[i].x, vB[i].y, vC[i].x, vC[i].y};
            #pragma unroll
            for (int p = 0; p < 2; ++p) {
                // 5 x v_pk_add_f32: {v,v} splat is an op_sel modifier (free)
                const f32x2 t0 = (f32x2){v[p + 0], v[p + 0]} + wp0;
                const f32x2 t1 = (f32x2){v[p + 1], v[p + 1]} + wp1;
                const f32x2 t2 = (f32x2){v[p + 2], v[p + 2]} + wp2;
                const f32x2 t3 = (f32x2){v[p + 3], v[p + 3]} + wp3;
                const f32x2 t4 = (f32x2){v[p + 4], v[p + 4]} + wp4;
                f32x2& acc = p ? acc1 : acc0;
                // shaped for max3: (acc,t0,t1) and (t2,t3,t4) then combine
                acc.x = fmaxf(fmaxf(fmaxf(acc.x, t0.x), t1.x),
                              fmaxf(fmaxf(t2.x, t3.x), t4.x));
                acc.y = fmaxf(fmaxf(fmaxf(acc.y, t0.y), t1.y),
                              fmaxf(fmaxf(t2.y, t3.y), t4.y));
            }
        }
    }

    // ---- write out: float2 per o (x even => x+1 in range whenever x is) ----
    const int y = y0 + ty;
    const int x = x0 + tx * 2;
    const int o0 = wave * 2;
    if (y < HO && x < WO) {
        float2 s0; s0.x = acc0.x; s0.y = acc1.x;   // o0: px0, px1
        float2 s1; s1.x = acc0.y; s1.y = acc1.y;   // o1: px0, px1
        *(float2*)&out[(((size_t)b * CO + o0) * HO + y) * WO + x] = s0;
        *(float2*)&out[(((size_t)b * CO + o0 + 1) * HO + y) * WO + x] = s1;
    }
}

extern "C" void kernel_launch(void* const* d_in, const int* in_sizes, int n_in,
                              void* d_out, int out_size, void* d_ws, size_t ws_size,
                              hipStream_t stream)
{
    const float* img  = (const float*)d_in[0];
    const float* kern = (const float*)d_in[1];
    float* out = (float*)d_out;

    dim3 grid((WO + TILE_X - 1) / TILE_X,   // 8
              (HO + TILE_Y - 1) / TILE_Y,   // 16
              B_);                          // 4  -> 512 blocks
    dim3 block(THREADS);
    maxplus_conv12<<<grid, block, 0, stream>>>(img, kern, out);
}